// Round 7
// baseline (199.221 us; speedup 1.0000x reference)
//
#include <hip/hip_runtime.h>
#include <hip/hip_bf16.h>
#include <stdint.h>

#define N_MODELS 16
#define IN_F 1024
#define OUT_F 1024
#define N_TOK 8192
#define MAX_MT 80          // max m-tiles: 64 full + up to 15 fragmentation

typedef unsigned short u16;
using us4   = __attribute__((ext_vector_type(4))) unsigned short;
using s16x8 = __attribute__((ext_vector_type(8))) short;
using f32x4 = __attribute__((ext_vector_type(4))) float;

__device__ __forceinline__ u16 f2bf(float f) {
    union { float f; uint32_t u; } v;
    v.f = f;
    uint32_t u = v.u;
    u += 0x7fffu + ((u >> 16) & 1u);   // RNE
    return (u16)(u >> 16);
}

__device__ __forceinline__ void gload16(const u16* g, u16* l) {
    // async global->LDS DMA, 16 B/lane; LDS dest = wave-uniform base + lane*16
    __builtin_amdgcn_global_load_lds(
        (const __attribute__((address_space(1))) void*)g,
        (__attribute__((address_space(3))) void*)l, 16, 0, 0);
}

// ---------------- kernel 1: setup (bx 0) + w-convert (bx 1..2048) + x-gather (bx 2049..2560) ----------------
// NO cross-block dependencies: each x-block recomputes the histogram+scan from idxs
// (32 KB, L2-hot) itself and derives its own tokens' destination rows. The scan is the
// exact same deterministic computation as setup's, so the xg row <-> perm bijection is
// guaranteed identical. x-blocks' VALU/LDS scan work overlaps the BW-bound w-path.
// wT layout (u16): (e*8 + nt)*131072 + ko_g*1024 + n*8 + j    (ko_g: global k-octet 0..127)
// xg layout (u16): mt*131072 + kb*4096 + q*1024 + r*8 + j     (k = kb*32 + q*8 + j)
// xg pad rows (beyond each expert's count) are left UNWRITTEN (poison): MFMA rows are
// independent and the gemm epilogue discards rows >= mValid, so this is safe.
#define ROW 17   // LDS row stride (ints) for [256][16] tables -> conflict-free
#define WBLOCKS 2048       // (e, nt, 64-k group)
#define XBLOCKS2 512       // (token-group g 0..63, 128-k slice kg 0..7)

__global__ __launch_bounds__(256)
void prep_kernel(const float* __restrict__ w, const float* __restrict__ x,
                 const int* __restrict__ idxs,
                 int* __restrict__ perm,
                 int* __restrict__ offs,       // [17]
                 int* __restrict__ tile_off,   // [17]
                 u16* __restrict__ wT, u16* __restrict__ xg)
{
    __shared__ int cnt[256 * ROW];
    __shared__ int offsS[N_MODELS + 1];
    __shared__ int tileS[N_MODELS + 1];
    __shared__ int destS[128];
    int t  = threadIdx.x;
    int bx = blockIdx.x;

    if (bx == 0) {
        // ---- setup: histogram + scan + rank scatter (for the GEMM's perm/offs/tile_off) ----
#pragma unroll
        for (int e = 0; e < N_MODELS; ++e) cnt[t * ROW + e] = 0;
        __syncthreads();

        int base = t * 32;
#pragma unroll
        for (int i = 0; i < 32; ++i) cnt[t * ROW + idxs[base + i]] += 1;
        __syncthreads();

#pragma unroll
        for (int s = 1; s < 256; s <<= 1) {
            int v[N_MODELS];
#pragma unroll
            for (int e = 0; e < N_MODELS; ++e)
                v[e] = (t >= s) ? cnt[(t - s) * ROW + e] : 0;
            __syncthreads();
#pragma unroll
            for (int e = 0; e < N_MODELS; ++e)
                cnt[t * ROW + e] += v[e];
            __syncthreads();
        }

        if (t == 0) {
            int o = 0, to = 0;
            for (int e = 0; e < N_MODELS; ++e) {
                int c = cnt[255 * ROW + e];
                offsS[e] = o;
                offs[e] = o; tile_off[e] = to;
                to += (c + 127) >> 7;
                o  += c;
            }
            offsS[N_MODELS] = o;
            offs[N_MODELS] = o; tile_off[N_MODELS] = to;
        }
        __syncthreads();

        int cur[N_MODELS];
#pragma unroll
        for (int e = 0; e < N_MODELS; ++e)
            cur[e] = offsS[e] + ((t > 0) ? cnt[(t - 1) * ROW + e] : 0);
        __syncthreads();
#pragma unroll
        for (int e = 0; e < N_MODELS; ++e) cnt[t * ROW + e] = cur[e];

#pragma unroll
        for (int i = 0; i < 32; ++i) {
            int tok = base + i;
            int e = idxs[tok];
            perm[cnt[t * ROW + e]++] = tok;
        }
        return;
    }

    if (bx <= WBLOCKS) {
        // ---- w-path: direct strided-coalesced transform, no LDS / no barriers ----
        int wb = bx - 1;             // 0..2047
        int e  = wb >> 7;
        int nt = (wb >> 4) & 7;
        int kg = wb & 15;            // 64-k group
        int n    = t & 127;          // lane-contiguous output column
        int half = t >> 7;

        const float* wp = w  + (size_t)e * (IN_F * OUT_F) + (size_t)nt * 128 + n;
        u16*         ob = wT + ((size_t)(e * 8 + nt)) * 131072 + (size_t)n * 8;

#pragma unroll
        for (int i = 0; i < 4; ++i) {
            int kog = kg * 8 + half + i * 2;   // global k-octet
            float r[8];
#pragma unroll
            for (int j = 0; j < 8; ++j)
                r[j] = wp[(size_t)(kog * 8 + j) * OUT_F];   // 256 B/wave contiguous per instr
            union { __hip_bfloat162 h; uint32_t u; } c0, c1, c2, c3;
            c0.h = __float22bfloat162_rn(make_float2(r[0], r[1]));
            c1.h = __float22bfloat162_rn(make_float2(r[2], r[3]));
            c2.h = __float22bfloat162_rn(make_float2(r[4], r[5]));
            c3.h = __float22bfloat162_rn(make_float2(r[6], r[7]));
            union { s16x8 v; uint32_t u[4]; } outv;
            outv.u[0] = c0.u; outv.u[1] = c1.u; outv.u[2] = c2.u; outv.u[3] = c3.u;
            *(s16x8*)(ob + (size_t)kog * 1024) = outv.v;    // 1 KB/wave contiguous
        }
        return;
    }

    // ---- x-path (source-organized, self-sufficient): local scan -> dest rows -> gather ----
    int bx2 = bx - (WBLOCKS + 1);   // 0..511
    int g   = bx2 >> 3;             // token group: tokens g*128 .. g*128+127
    int kg  = bx2 & 7;              // 128-k slice

    // full histogram + inclusive per-thread-row scan (identical computation to setup)
#pragma unroll
    for (int e = 0; e < N_MODELS; ++e) cnt[t * ROW + e] = 0;
    __syncthreads();

    int base = t * 32;
#pragma unroll
    for (int i = 0; i < 32; ++i) cnt[t * ROW + idxs[base + i]] += 1;
    __syncthreads();

#pragma unroll
    for (int s = 1; s < 256; s <<= 1) {
        int v[N_MODELS];
#pragma unroll
        for (int e = 0; e < N_MODELS; ++e)
            v[e] = (t >= s) ? cnt[(t - s) * ROW + e] : 0;
        __syncthreads();
#pragma unroll
        for (int e = 0; e < N_MODELS; ++e)
            cnt[t * ROW + e] += v[e];
        __syncthreads();
    }

    if (t == 0) {
        int to = 0;
        for (int e = 0; e < N_MODELS; ++e) {
            tileS[e] = to;
            to += (cnt[255 * ROW + e] + 127) >> 7;
        }
    }
    __syncthreads();

    // threads 0..3 walk this group's 4 source thread-chunks in setup's exact order,
    // producing tile-space dest v = (tile_off[e]<<7) + local_rank  ->  mt = v>>7, r = v&127
    if (t < 4) {
        int tr = g * 4 + t;          // thread-row in setup's partition
        int curL[N_MODELS];
#pragma unroll
        for (int e = 0; e < N_MODELS; ++e)
            curL[e] = (tr > 0) ? cnt[(tr - 1) * ROW + e] : 0;   // local rank within expert
        for (int i = 0; i < 32; ++i) {
            int tok = tr * 32 + i;
            int e = idxs[tok];
            destS[t * 32 + i] = (tileS[e] << 7) + curL[e]++;
        }
    }
    __syncthreads();

    // gather: 128 tokens x 128-k slice; reads 128 B-coalesced per (token, 32-k);
    // writes ~32 B-granular scatter by dest row (L2-absorbed)
    int r0   = t >> 3;           // local token 0..31 (+ i*32)
    int apos = t & 7;
    int q    = apos >> 1;
    int j0   = (apos & 1) * 4;

#pragma unroll
    for (int kb4 = 0; kb4 < 4; ++kb4) {
        int kb = kg * 4 + kb4;
        int k  = kb * 32 + apos * 4;
#pragma unroll
        for (int i = 0; i < 4; ++i) {
            int lt  = r0 + i * 32;
            int tok = g * 128 + lt;
            int d   = destS[lt];
            const float4 v = *(const float4*)(x + (size_t)tok * IN_F + k);
            us4 pk; pk.x = f2bf(v.x); pk.y = f2bf(v.y); pk.z = f2bf(v.z); pk.w = f2bf(v.w);
            *(us4*)(xg + (size_t)(d >> 7) * 131072 + (size_t)kb * 4096
                       + (size_t)q * 1024 + (d & 127) * 8 + j0) = pk;
        }
    }
}

// ---------------- kernel 2: grouped GEMM + bias + relu (round-3 verified, unchanged) ----------------
//  (a) A-operand direct global->VGPR from frag-major xg (L2-resident via XCD swizzle);
//      a0/a1 register rotation prefetches a full compute phase ahead. A never touches LDS.
//  (b) B double-buffered in LDS via global_load_lds, staged right after the barrier
//      (T3-minimum 2-phase). 1 barrier per 64-k step.
__global__ __launch_bounds__(256, 3)
void gemm_kernel(const u16* __restrict__ xg, const u16* __restrict__ wT,
                 const float* __restrict__ bias,
                 const int* __restrict__ perm, const int* __restrict__ offs,
                 const int* __restrict__ tile_off,
                 float* __restrict__ out)
{
    __shared__ u16 Bs[2][8192];      // 32 KB: double-buffered 64-k B tile
    __shared__ int   permS[128];
    __shared__ float biasS[128];
    __shared__ int   toS[N_MODELS + 1];

    int t = threadIdx.x;
    // XCD-chunked bijective swizzle (640 = 8 x 80): each XCD gets 10 consecutive
    // bt x all 8 nt -> xg tiles and wT panels stay in that XCD's L2.
    int o    = blockIdx.x;               // 0..639
    int wgid = (o & 7) * MAX_MT + (o >> 3);
    int bt   = wgid >> 3;                // m-tile id
    int nt   = wgid & 7;                 // n-tile id

    if (t <= N_MODELS) toS[t] = tile_off[t];
    __syncthreads();
    if (bt >= toS[N_MODELS]) return;   // uniform

    int e = 0;
    while (toS[e + 1] <= bt) ++e;
    int s0   = offs[e] + (bt - toS[e]) * 128;
    int sEnd = offs[e + 1];
    int mValid = sEnd - s0; if (mValid > 128) mValid = 128;

    if (t < 128) {
        permS[t] = (s0 + t < sEnd) ? perm[s0 + t] : 0;
        biasS[t] = bias[(size_t)e * OUT_F + nt * 128 + t];
    }
    // published by the loop's first __syncthreads()

    const u16* atile = xg + (size_t)bt * 131072;
    const u16* btile = wT + ((size_t)(e * 8 + nt)) * 131072;

    int lane = t & 63;
    int wv   = t >> 6;
    int wm   = (wv >> 1) * 64;
    int wn   = (wv & 1) * 64;
    int m    = lane & 15;
    int q    = lane >> 4;

    int aoff = q * 1024 + (wm + m) * 8;   // u16 offset of this lane's A frag in a 32-k slab
    int boff = q * 1024 + (wn + m) * 8;   // same for B within staged LDS slab

    f32x4 acc[4][4];
#pragma unroll
    for (int i = 0; i < 4; ++i)
#pragma unroll
        for (int j = 0; j < 4; ++j)
            acc[i][j] = (f32x4){0.f, 0.f, 0.f, 0.f};

    // prologue: stage B(kb2=0), load A slab0+slab1 of kb2=0 into registers
#pragma unroll
    for (int i = 0; i < 4; ++i)
        gload16(btile + wv * 2048 + i * 512 + lane * 8, &Bs[0][wv * 2048 + i * 512]);

    s16x8 a0[4], a1[4];
#pragma unroll
    for (int mt2 = 0; mt2 < 4; ++mt2)
        a0[mt2] = *(const s16x8*)(atile + aoff + mt2 * 128);
#pragma unroll
    for (int mt2 = 0; mt2 < 4; ++mt2)
        a1[mt2] = *(const s16x8*)(atile + 4096 + aoff + mt2 * 128);

    for (int kb2 = 0; kb2 < 16; ++kb2) {
        int cur = kb2 & 1;
        __syncthreads();   // auto vmcnt(0) drain: B(kb2) + in-flight A-loads complete
        if (kb2 < 15) {
            const u16* gb = btile + (size_t)(kb2 + 1) * 8192;
#pragma unroll
            for (int i = 0; i < 4; ++i)
                gload16(gb + wv * 2048 + i * 512 + lane * 8,
                        &Bs[cur ^ 1][wv * 2048 + i * 512]);
        }
        if (kb2 > 0) {   // A slab1 of THIS kb2; covered by slab0 compute below
#pragma unroll
            for (int mt2 = 0; mt2 < 4; ++mt2)
                a1[mt2] = *(const s16x8*)(atile + (size_t)kb2 * 8192 + 4096 + aoff + mt2 * 128);
        }

        // ---- slab 0 ----
        s16x8 bf[4];
#pragma unroll
        for (int nt2 = 0; nt2 < 4; ++nt2)
            bf[nt2] = *(const s16x8*)(&Bs[cur][boff + nt2 * 128]);
#pragma unroll
        for (int mt2 = 0; mt2 < 4; ++mt2)
#pragma unroll
            for (int nt2 = 0; nt2 < 4; ++nt2)
                acc[mt2][nt2] = __builtin_amdgcn_mfma_f32_16x16x32_bf16(
                    a0[mt2], bf[nt2], acc[mt2][nt2], 0, 0, 0);

        if (kb2 < 15) {   // A slab0 of NEXT kb2; flies during slab1 compute + drain
#pragma unroll
            for (int mt2 = 0; mt2 < 4; ++mt2)
                a0[mt2] = *(const s16x8*)(atile + (size_t)(kb2 + 1) * 8192 + aoff + mt2 * 128);
        }

        // ---- slab 1 ----
#pragma unroll
        for (int nt2 = 0; nt2 < 4; ++nt2)
            bf[nt2] = *(const s16x8*)(&Bs[cur][4096 + boff + nt2 * 128]);
#pragma unroll
        for (int mt2 = 0; mt2 < 4; ++mt2)
#pragma unroll
            for (int nt2 = 0; nt2 < 4; ++nt2)
                acc[mt2][nt2] = __builtin_amdgcn_mfma_f32_16x16x32_bf16(
                    a1[mt2], bf[nt2], acc[mt2][nt2], 0, 0, 0);
    }

    // epilogue: bias + relu, scatter rows by perm
#pragma unroll
    for (int mt2 = 0; mt2 < 4; ++mt2) {
        int rbase = wm + mt2 * 16 + q * 4;
#pragma unroll
        for (int i = 0; i < 4; ++i) {
            int r = rbase + i;
            if (r < mValid) {
                int tok = permS[r];
                float* orow = out + (size_t)tok * OUT_F + nt * 128;
#pragma unroll
                for (int nt2 = 0; nt2 < 4; ++nt2) {
                    int col = wn + nt2 * 16 + m;
                    float v = acc[mt2][nt2][i] + biasS[col];
                    orow[col] = v > 0.f ? v : 0.f;
                }
            }
        }
    }
}

extern "C" void kernel_launch(void* const* d_in, const int* in_sizes, int n_in,
                              void* d_out, int out_size, void* d_ws, size_t ws_size,
                              hipStream_t stream) {
    const float* x    = (const float*)d_in[0];
    const int*   idxs = (const int*)d_in[1];
    const float* w    = (const float*)d_in[2];
    const float* b    = (const float*)d_in[3];
    float* out = (float*)d_out;

    // ws layout: wT u16[16M] (32 MB) | xg u16[80*32*4096] (20 MB) | perm | offs | tile_off
    u16* wT = (u16*)d_ws;
    u16* xg = wT + (size_t)N_MODELS * IN_F * OUT_F;
    int* perm     = (int*)(xg + (size_t)MAX_MT * 32 * 4096);
    int* offs     = perm + N_TOK;
    int* tile_off = offs + (N_MODELS + 1);

    prep_kernel<<<1 + WBLOCKS + XBLOCKS2, 256, 0, stream>>>(
        w, x, idxs, perm, offs, tile_off, wT, xg);
    gemm_kernel<<<8 * MAX_MT, 256, 0, stream>>>(xg, wT, b, perm, offs, tile_off, out);
}

// Round 8
// 183.079 us; speedup vs baseline: 1.0882x; 1.0882x over previous
//
#include <hip/hip_runtime.h>
#include <hip/hip_bf16.h>
#include <stdint.h>

#define N_MODELS 16
#define IN_F 1024
#define OUT_F 1024
#define N_TOK 8192
#define MAX_MT 80          // max m-tiles: 64 full + up to 15 fragmentation

typedef unsigned short u16;
using us4   = __attribute__((ext_vector_type(4))) unsigned short;
using s16x8 = __attribute__((ext_vector_type(8))) short;
using f32x4 = __attribute__((ext_vector_type(4))) float;

__device__ __forceinline__ u16 f2bf(float f) {
    union { float f; uint32_t u; } v;
    v.f = f;
    uint32_t u = v.u;
    u += 0x7fffu + ((u >> 16) & 1u);   // RNE
    return (u16)(u >> 16);
}

// pack 8 fp32 (ascending k) -> 8 bf16 RNE
__device__ __forceinline__ s16x8 pack8(const float* r) {
    union { __hip_bfloat162 h; uint32_t u; } c0, c1, c2, c3;
    c0.h = __float22bfloat162_rn(make_float2(r[0], r[1]));
    c1.h = __float22bfloat162_rn(make_float2(r[2], r[3]));
    c2.h = __float22bfloat162_rn(make_float2(r[4], r[5]));
    c3.h = __float22bfloat162_rn(make_float2(r[6], r[7]));
    union { s16x8 v; uint32_t u[4]; } outv;
    outv.u[0] = c0.u; outv.u[1] = c1.u; outv.u[2] = c2.u; outv.u[3] = c3.u;
    return outv.v;
}

// ---------------- kernel 1: setup (bx 0) + self-scan x-gather (bx 1..512) ----------------
// No cross-block dependencies: each x-block recomputes the histogram+scan from idxs
// (32 KB, L2-hot) and derives its own 128 tokens' destination rows — deterministically
// identical bijection to setup's perm (verified round 7).
// xg layout (u16): mt*131072 + kb*4096 + q*1024 + r*8 + j     (k = kb*32 + q*8 + j)
// xg pad rows (beyond each expert's count) stay unwritten (poison): rows >= mValid are
// discarded in the gemm epilogue, and MFMA rows are independent.
#define ROW 17   // LDS row stride (ints) for [256][16] tables -> conflict-free
#define XBLOCKS2 512       // (token-group g 0..63, 128-k slice kg 0..7)

__global__ __launch_bounds__(256)
void xsetup_kernel(const float* __restrict__ x,
                   const int* __restrict__ idxs,
                   int* __restrict__ perm,
                   int* __restrict__ offs,       // [17]
                   int* __restrict__ tile_off,   // [17]
                   u16* __restrict__ xg)
{
    __shared__ int cnt[256 * ROW];
    __shared__ int offsS[N_MODELS + 1];
    __shared__ int tileS[N_MODELS + 1];
    __shared__ int destS[128];
    int t  = threadIdx.x;
    int bx = blockIdx.x;

    if (bx == 0) {
        // ---- setup: histogram + scan + rank scatter (for the GEMM's perm/offs/tile_off) ----
#pragma unroll
        for (int e = 0; e < N_MODELS; ++e) cnt[t * ROW + e] = 0;
        __syncthreads();

        int base = t * 32;
#pragma unroll
        for (int i = 0; i < 32; ++i) cnt[t * ROW + idxs[base + i]] += 1;
        __syncthreads();

#pragma unroll
        for (int s = 1; s < 256; s <<= 1) {
            int v[N_MODELS];
#pragma unroll
            for (int e = 0; e < N_MODELS; ++e)
                v[e] = (t >= s) ? cnt[(t - s) * ROW + e] : 0;
            __syncthreads();
#pragma unroll
            for (int e = 0; e < N_MODELS; ++e)
                cnt[t * ROW + e] += v[e];
            __syncthreads();
        }

        if (t == 0) {
            int o = 0, to = 0;
            for (int e = 0; e < N_MODELS; ++e) {
                int c = cnt[255 * ROW + e];
                offsS[e] = o;
                offs[e] = o; tile_off[e] = to;
                to += (c + 127) >> 7;
                o  += c;
            }
            offsS[N_MODELS] = o;
            offs[N_MODELS] = o; tile_off[N_MODELS] = to;
        }
        __syncthreads();

        int cur[N_MODELS];
#pragma unroll
        for (int e = 0; e < N_MODELS; ++e)
            cur[e] = offsS[e] + ((t > 0) ? cnt[(t - 1) * ROW + e] : 0);
        __syncthreads();
#pragma unroll
        for (int e = 0; e < N_MODELS; ++e) cnt[t * ROW + e] = cur[e];

#pragma unroll
        for (int i = 0; i < 32; ++i) {
            int tok = base + i;
            int e = idxs[tok];
            perm[cnt[t * ROW + e]++] = tok;
        }
        return;
    }

    // ---- x-path (source-organized, self-sufficient): local scan -> dest rows -> gather ----
    int bx2 = bx - 1;               // 0..511
    int g   = bx2 >> 3;             // token group: tokens g*128 .. g*128+127
    int kg  = bx2 & 7;              // 128-k slice

    // full histogram + inclusive per-thread-row scan (identical computation to setup)
#pragma unroll
    for (int e = 0; e < N_MODELS; ++e) cnt[t * ROW + e] = 0;
    __syncthreads();

    int base = t * 32;
#pragma unroll
    for (int i = 0; i < 32; ++i) cnt[t * ROW + idxs[base + i]] += 1;
    __syncthreads();

#pragma unroll
    for (int s = 1; s < 256; s <<= 1) {
        int v[N_MODELS];
#pragma unroll
        for (int e = 0; e < N_MODELS; ++e)
            v[e] = (t >= s) ? cnt[(t - s) * ROW + e] : 0;
        __syncthreads();
#pragma unroll
        for (int e = 0; e < N_MODELS; ++e)
            cnt[t * ROW + e] += v[e];
        __syncthreads();
    }

    if (t == 0) {
        int to = 0;
        for (int e = 0; e < N_MODELS; ++e) {
            tileS[e] = to;
            to += (cnt[255 * ROW + e] + 127) >> 7;
        }
    }
    __syncthreads();

    // threads 0..3 walk this group's 4 source thread-chunks in setup's exact order
    if (t < 4) {
        int tr = g * 4 + t;          // thread-row in setup's partition
        int curL[N_MODELS];
#pragma unroll
        for (int e = 0; e < N_MODELS; ++e)
            curL[e] = (tr > 0) ? cnt[(tr - 1) * ROW + e] : 0;   // local rank within expert
        for (int i = 0; i < 32; ++i) {
            int tok = tr * 32 + i;
            int e = idxs[tok];
            destS[t * 32 + i] = (tileS[e] << 7) + curL[e]++;
        }
    }
    __syncthreads();

    // gather: 128 tokens x 128-k slice; reads 128 B-coalesced per (token, 32-k)
    int r0   = t >> 3;           // local token 0..31 (+ i*32)
    int apos = t & 7;
    int q    = apos >> 1;
    int j0   = (apos & 1) * 4;

#pragma unroll
    for (int kb4 = 0; kb4 < 4; ++kb4) {
        int kb = kg * 4 + kb4;
        int k  = kb * 32 + apos * 4;
#pragma unroll
        for (int i = 0; i < 4; ++i) {
            int lt  = r0 + i * 32;
            int tok = g * 128 + lt;
            int d   = destS[lt];
            const float4 v = *(const float4*)(x + (size_t)tok * IN_F + k);
            us4 pk; pk.x = f2bf(v.x); pk.y = f2bf(v.y); pk.z = f2bf(v.z); pk.w = f2bf(v.w);
            *(us4*)(xg + (size_t)(d >> 7) * 131072 + (size_t)kb * 4096
                       + (size_t)q * 1024 + (d & 127) * 8 + j0) = pk;
        }
    }
}

// ---------------- kernel 2: grouped GEMM, B straight from w (fp32) + bias + relu ----------------
// wT eliminated: B is read from w fp32 (dense, block-uniform, 256 B/wave coalesced; ~3/4
// L2-hits via the XCD swizzle's 4x bt-reuse per (e,nt) panel), converted to bf16 in-register,
// and reg-staged into the SAME frag-major LDS layout the verified ds_read path uses.
// Single barrier per 64-k step, stage(buf^1)-then-compute(buf) order; raw fp32 for step
// kb2+2 issued at step kb2 (one full compute phase + barrier of latency cover).
// A-path (direct from xg, a0/a1 rotation), epilogue, swizzle: identical to round 3.
__global__ __launch_bounds__(256, 3)
void gemm_kernel(const u16* __restrict__ xg, const float* __restrict__ w,
                 const float* __restrict__ bias,
                 const int* __restrict__ perm, const int* __restrict__ offs,
                 const int* __restrict__ tile_off,
                 float* __restrict__ out)
{
    __shared__ u16 Bs[2][8192];      // 32 KB: double-buffered 64-k B tile (bf16 frag-major)
    __shared__ int   permS[128];
    __shared__ float biasS[128];
    __shared__ int   toS[N_MODELS + 1];

    int t = threadIdx.x;
    // XCD-chunked bijective swizzle (640 = 8 x 80)
    int o    = blockIdx.x;               // 0..639
    int wgid = (o & 7) * MAX_MT + (o >> 3);
    int bt   = wgid >> 3;                // m-tile id
    int nt   = wgid & 7;                 // n-tile id

    if (t <= N_MODELS) toS[t] = tile_off[t];
    __syncthreads();
    if (bt >= toS[N_MODELS]) return;   // uniform

    int e = 0;
    while (toS[e + 1] <= bt) ++e;
    int s0   = offs[e] + (bt - toS[e]) * 128;
    int sEnd = offs[e + 1];
    int mValid = sEnd - s0; if (mValid > 128) mValid = 128;

    if (t < 128) {
        permS[t] = (s0 + t < sEnd) ? perm[s0 + t] : 0;
        biasS[t] = bias[(size_t)e * OUT_F + nt * 128 + t];
    }
    // published by the loop's first __syncthreads()

    const u16* atile = xg + (size_t)bt * 131072;

    // ---- B staging geometry: thread covers column n, k-octets ko = kh + 2i ----
    int n  = t & 127;                 // output column within the 128-col panel
    int kh = t >> 7;                  // 0..1
    const float* wbase = w + (size_t)e * (IN_F * OUT_F) + (size_t)kh * 8 * OUT_F
                           + (size_t)nt * 128 + n;
    int n8 = n * 8;                   // u16 offset of this thread's b128 write

    int lane = t & 63;
    int wv   = t >> 6;
    int wm   = (wv >> 1) * 64;
    int wn   = (wv & 1) * 64;
    int m    = lane & 15;
    int q    = lane >> 4;

    int aoff = q * 1024 + (wm + m) * 8;   // A frag offset within a 32-k slab of xg
    int boff = q * 1024 + (wn + m) * 8;   // B frag offset within a staged 32-k LDS slab

    f32x4 acc[4][4];
#pragma unroll
    for (int i = 0; i < 4; ++i)
#pragma unroll
        for (int j = 0; j < 4; ++j)
            acc[i][j] = (f32x4){0.f, 0.f, 0.f, 0.f};

    float fr[4][8];   // raw fp32 B for the NEXT K-step (i = octet pair index)

    // prologue: raw(kb2=0) -> pack -> Bs[0]; then raw(kb2=1) into fr; A slabs of kb2=0
#pragma unroll
    for (int i = 0; i < 4; ++i)
#pragma unroll
        for (int j = 0; j < 8; ++j)
            fr[i][j] = wbase[(size_t)(i * 16 + j) * OUT_F];
#pragma unroll
    for (int i = 0; i < 4; ++i) {
        int ko = kh + 2 * i;
        *(s16x8*)(&Bs[0][(ko >> 2) * 4096 + (ko & 3) * 1024 + n8]) = pack8(fr[i]);
    }
#pragma unroll
    for (int i = 0; i < 4; ++i)
#pragma unroll
        for (int j = 0; j < 8; ++j)
            fr[i][j] = wbase[(size_t)(64 + i * 16 + j) * OUT_F];

    s16x8 a0[4], a1[4];
#pragma unroll
    for (int mt2 = 0; mt2 < 4; ++mt2)
        a0[mt2] = *(const s16x8*)(atile + aoff + mt2 * 128);
#pragma unroll
    for (int mt2 = 0; mt2 < 4; ++mt2)
        a1[mt2] = *(const s16x8*)(atile + 4096 + aoff + mt2 * 128);

    for (int kb2 = 0; kb2 < 16; ++kb2) {
        int cur = kb2 & 1;
        __syncthreads();   // prev compute done; Bs[cur] (written last iter) visible

        // stage B(kb2+1) into Bs[cur^1] from fr, then issue raw(kb2+2)
        if (kb2 < 15) {
#pragma unroll
            for (int i = 0; i < 4; ++i) {
                int ko = kh + 2 * i;
                *(s16x8*)(&Bs[cur ^ 1][(ko >> 2) * 4096 + (ko & 3) * 1024 + n8]) = pack8(fr[i]);
            }
        }
        if (kb2 < 14) {
#pragma unroll
            for (int i = 0; i < 4; ++i)
#pragma unroll
                for (int j = 0; j < 8; ++j)
                    fr[i][j] = wbase[(size_t)((kb2 + 2) * 64 + i * 16 + j) * OUT_F];
        }
        if (kb2 > 0) {   // A slab1 of THIS kb2; covered by slab0 compute below
#pragma unroll
            for (int mt2 = 0; mt2 < 4; ++mt2)
                a1[mt2] = *(const s16x8*)(atile + (size_t)kb2 * 8192 + 4096 + aoff + mt2 * 128);
        }

        // ---- slab 0 ----
        s16x8 bf[4];
#pragma unroll
        for (int nt2 = 0; nt2 < 4; ++nt2)
            bf[nt2] = *(const s16x8*)(&Bs[cur][boff + nt2 * 128]);
#pragma unroll
        for (int mt2 = 0; mt2 < 4; ++mt2)
#pragma unroll
            for (int nt2 = 0; nt2 < 4; ++nt2)
                acc[mt2][nt2] = __builtin_amdgcn_mfma_f32_16x16x32_bf16(
                    a0[mt2], bf[nt2], acc[mt2][nt2], 0, 0, 0);

        if (kb2 < 15) {   // A slab0 of NEXT kb2; flies during slab1 compute
#pragma unroll
            for (int mt2 = 0; mt2 < 4; ++mt2)
                a0[mt2] = *(const s16x8*)(atile + (size_t)(kb2 + 1) * 8192 + aoff + mt2 * 128);
        }

        // ---- slab 1 ----
#pragma unroll
        for (int nt2 = 0; nt2 < 4; ++nt2)
            bf[nt2] = *(const s16x8*)(&Bs[cur][4096 + boff + nt2 * 128]);
#pragma unroll
        for (int mt2 = 0; mt2 < 4; ++mt2)
#pragma unroll
            for (int nt2 = 0; nt2 < 4; ++nt2)
                acc[mt2][nt2] = __builtin_amdgcn_mfma_f32_16x16x32_bf16(
                    a1[mt2], bf[nt2], acc[mt2][nt2], 0, 0, 0);
    }

    // epilogue: bias + relu, scatter rows by perm
#pragma unroll
    for (int mt2 = 0; mt2 < 4; ++mt2) {
        int rbase = wm + mt2 * 16 + q * 4;
#pragma unroll
        for (int i = 0; i < 4; ++i) {
            int r = rbase + i;
            if (r < mValid) {
                int tok = permS[r];
                float* orow = out + (size_t)tok * OUT_F + nt * 128;
#pragma unroll
                for (int nt2 = 0; nt2 < 4; ++nt2) {
                    int col = wn + nt2 * 16 + m;
                    float v = acc[mt2][nt2][i] + biasS[col];
                    orow[col] = v > 0.f ? v : 0.f;
                }
            }
        }
    }
}

extern "C" void kernel_launch(void* const* d_in, const int* in_sizes, int n_in,
                              void* d_out, int out_size, void* d_ws, size_t ws_size,
                              hipStream_t stream) {
    const float* x    = (const float*)d_in[0];
    const int*   idxs = (const int*)d_in[1];
    const float* w    = (const float*)d_in[2];
    const float* b    = (const float*)d_in[3];
    float* out = (float*)d_out;

    // ws layout: xg u16[80*32*4096] (20 MB) | perm | offs | tile_off
    u16* xg = (u16*)d_ws;
    int* perm     = (int*)(xg + (size_t)MAX_MT * 32 * 4096);
    int* offs     = perm + N_TOK;
    int* tile_off = offs + (N_MODELS + 1);

    xsetup_kernel<<<1 + XBLOCKS2, 256, 0, stream>>>(x, idxs, perm, offs, tile_off, xg);
    gemm_kernel<<<8 * MAX_MT, 256, 0, stream>>>(xg, w, b, perm, offs, tile_off, out);
}

// Round 9
// 180.913 us; speedup vs baseline: 1.1012x; 1.0120x over previous
//
#include <hip/hip_runtime.h>
#include <hip/hip_bf16.h>
#include <stdint.h>

#define N_MODELS 16
#define IN_F 1024
#define OUT_F 1024
#define N_TOK 8192
#define MAX_MT 80          // max m-tiles: 64 full + up to 15 fragmentation

typedef unsigned short u16;
using us4   = __attribute__((ext_vector_type(4))) unsigned short;
using s16x8 = __attribute__((ext_vector_type(8))) short;
using f32x4 = __attribute__((ext_vector_type(4))) float;

__device__ __forceinline__ u16 f2bf(float f) {
    union { float f; uint32_t u; } v;
    v.f = f;
    uint32_t u = v.u;
    u += 0x7fffu + ((u >> 16) & 1u);   // RNE
    return (u16)(u >> 16);
}

__device__ __forceinline__ void gload16(const u16* g, u16* l) {
    // async global->LDS DMA, 16 B/lane; LDS dest = wave-uniform base + lane*16
    __builtin_amdgcn_global_load_lds(
        (const __attribute__((address_space(1))) void*)g,
        (__attribute__((address_space(3))) void*)l, 16, 0, 0);
}

// ---------------- kernel 1: fused w-convert (blocks 1..2048) + setup (block 0) ----------------
// wT layout (u16): (e*8 + nt)*131072 + ko_g*1024 + n*8 + j    (ko_g: global k-octet 0..127)
#define ROW 17   // LDS row stride (ints) for [256][16] tables -> conflict-free
#define WBLOCKS 2048   // (e, nt, 64-k group)

__global__ __launch_bounds__(256)
void wprep_setup_kernel(const float* __restrict__ w,
                        const int* __restrict__ idxs,
                        int* __restrict__ perm,
                        int* __restrict__ offs,       // [17]
                        int* __restrict__ tile_off,   // [17]
                        u16* __restrict__ wT)
{
    __shared__ int cnt[256 * ROW];
    __shared__ int offsS[N_MODELS + 1];
    int t  = threadIdx.x;
    int bx = blockIdx.x;

    if (bx == 0) {
        // ---- setup: histogram + scan + rank scatter ----
#pragma unroll
        for (int e = 0; e < N_MODELS; ++e) cnt[t * ROW + e] = 0;
        __syncthreads();

        int base = t * 32;
#pragma unroll
        for (int i = 0; i < 32; ++i) cnt[t * ROW + idxs[base + i]] += 1;
        __syncthreads();

#pragma unroll
        for (int s = 1; s < 256; s <<= 1) {
            int v[N_MODELS];
#pragma unroll
            for (int e = 0; e < N_MODELS; ++e)
                v[e] = (t >= s) ? cnt[(t - s) * ROW + e] : 0;
            __syncthreads();
#pragma unroll
            for (int e = 0; e < N_MODELS; ++e)
                cnt[t * ROW + e] += v[e];
            __syncthreads();
        }

        if (t == 0) {
            int o = 0, to = 0;
            for (int e = 0; e < N_MODELS; ++e) {
                int c = cnt[255 * ROW + e];
                offsS[e] = o;
                offs[e] = o; tile_off[e] = to;
                to += (c + 127) >> 7;
                o  += c;
            }
            offsS[N_MODELS] = o;
            offs[N_MODELS] = o; tile_off[N_MODELS] = to;
        }
        __syncthreads();

        int cur[N_MODELS];
#pragma unroll
        for (int e = 0; e < N_MODELS; ++e)
            cur[e] = offsS[e] + ((t > 0) ? cnt[(t - 1) * ROW + e] : 0);
        __syncthreads();
#pragma unroll
        for (int e = 0; e < N_MODELS; ++e) cnt[t * ROW + e] = cur[e];

#pragma unroll
        for (int i = 0; i < 32; ++i) {
            int tok = base + i;
            int e = idxs[tok];
            perm[cnt[t * ROW + e]++] = tok;
        }
        return;
    }

    // ---- w-path: direct strided-coalesced transform, no LDS / no barriers ----
    int wb = bx - 1;             // 0..2047
    int e  = wb >> 7;
    int nt = (wb >> 4) & 7;
    int kg = wb & 15;            // 64-k group
    int n    = t & 127;          // lane-contiguous output column
    int half = t >> 7;

    const float* wp = w  + (size_t)e * (IN_F * OUT_F) + (size_t)nt * 128 + n;
    u16*         ob = wT + ((size_t)(e * 8 + nt)) * 131072 + (size_t)n * 8;

#pragma unroll
    for (int i = 0; i < 4; ++i) {
        int kog = kg * 8 + half + i * 2;   // global k-octet
        float r[8];
#pragma unroll
        for (int j = 0; j < 8; ++j)
            r[j] = wp[(size_t)(kog * 8 + j) * OUT_F];   // 256 B/wave contiguous per instr
        union { __hip_bfloat162 h; uint32_t u; } c0, c1, c2, c3;
        c0.h = __float22bfloat162_rn(make_float2(r[0], r[1]));
        c1.h = __float22bfloat162_rn(make_float2(r[2], r[3]));
        c2.h = __float22bfloat162_rn(make_float2(r[4], r[5]));
        c3.h = __float22bfloat162_rn(make_float2(r[6], r[7]));
        union { s16x8 v; uint32_t u[4]; } outv;
        outv.u[0] = c0.u; outv.u[1] = c1.u; outv.u[2] = c2.u; outv.u[3] = c3.u;
        *(s16x8*)(ob + (size_t)kog * 1024) = outv.v;    // 1 KB/wave contiguous
    }
}

// ---------------- kernel 2: x-gather fp32 -> bf16 frag-major, NO LDS ----------------
// xg layout (u16): mt*131072 + kb*4096 + q*1024 + r*8 + j   (k = kb*32 + q*8 + j)
#define XBLOCKS (MAX_MT * 8)    // (mt, 128-k group)

__global__ __launch_bounds__(256)
void xprep_kernel(const float* __restrict__ x,
                  const int* __restrict__ perm, const int* __restrict__ offs,
                  const int* __restrict__ tile_off,
                  u16* __restrict__ xg)
{
    int t  = threadIdx.x;
    int bx = blockIdx.x;
    int mt = bx >> 3;
    int kg = bx & 7;             // 128-k group
    int total = tile_off[N_MODELS];
    if (mt >= total) return;
    int e = 0;
    while (tile_off[e + 1] <= mt) ++e;
    int s0   = offs[e] + (mt - tile_off[e]) * 128;
    int sEnd = offs[e + 1];

    int r0   = t >> 3;           // 0..31
    int apos = t & 7;
    int q    = apos >> 1;
    int j0   = (apos & 1) * 4;

    int toks[4];
#pragma unroll
    for (int i = 0; i < 4; ++i) {
        int r = r0 + i * 32;
        toks[i] = (s0 + r < sEnd) ? perm[s0 + r] : -1;
    }

    u16* outx = xg + (size_t)mt * 131072;
#pragma unroll
    for (int kb4 = 0; kb4 < 4; ++kb4) {
        int kb = kg * 4 + kb4;
        int k  = kb * 32 + apos * 4;
#pragma unroll
        for (int i = 0; i < 4; ++i) {
            int r = r0 + i * 32;
            float4 v;
            if (toks[i] >= 0) v = *(const float4*)(x + (size_t)toks[i] * IN_F + k);
            else              v = make_float4(0.f, 0.f, 0.f, 0.f);
            us4 pk; pk.x = f2bf(v.x); pk.y = f2bf(v.y); pk.z = f2bf(v.z); pk.w = f2bf(v.w);
            *(us4*)(outx + (size_t)kb * 4096 + (size_t)q * 1024 + r * 8 + j0) = pk;
        }
    }
}

// ---------------- kernel 3: grouped GEMM + bias + relu (round-3 + ping-pong A prefetch) ----------------
//  (a) A-operand direct global->VGPR from frag-major xg (L2-resident via XCD swizzle).
//      NEW: ping-pong register sets aA/aB — both slabs of step kb2+1 are issued right
//      after slab-0's MFMAs of step kb2 (cover = slab1 compute + drain + stage, vs the
//      old a1 load that had only slab-0 cover). Macro-unrolled x2: no register copies,
//      all indices compile-time.
//  (b) B double-buffered in LDS via global_load_lds, staged right after the barrier
//      (T3-minimum 2-phase). 1 barrier per 64-k step. Unchanged from round 3.
__global__ __launch_bounds__(256, 3)
void gemm_kernel(const u16* __restrict__ xg, const u16* __restrict__ wT,
                 const float* __restrict__ bias,
                 const int* __restrict__ perm, const int* __restrict__ offs,
                 const int* __restrict__ tile_off,
                 float* __restrict__ out)
{
    __shared__ u16 Bs[2][8192];      // 32 KB: double-buffered 64-k B tile
    __shared__ int   permS[128];
    __shared__ float biasS[128];
    __shared__ int   toS[N_MODELS + 1];

    int t = threadIdx.x;
    // XCD-chunked bijective swizzle (640 = 8 x 80): each XCD gets 10 consecutive
    // bt x all 8 nt -> xg tiles and wT panels stay in that XCD's L2.
    int o    = blockIdx.x;               // 0..639
    int wgid = (o & 7) * MAX_MT + (o >> 3);
    int bt   = wgid >> 3;                // m-tile id
    int nt   = wgid & 7;                 // n-tile id

    if (t <= N_MODELS) toS[t] = tile_off[t];
    __syncthreads();
    if (bt >= toS[N_MODELS]) return;   // uniform

    int e = 0;
    while (toS[e + 1] <= bt) ++e;
    int s0   = offs[e] + (bt - toS[e]) * 128;
    int sEnd = offs[e + 1];
    int mValid = sEnd - s0; if (mValid > 128) mValid = 128;

    if (t < 128) {
        permS[t] = (s0 + t < sEnd) ? perm[s0 + t] : 0;
        biasS[t] = bias[(size_t)e * OUT_F + nt * 128 + t];
    }
    // published by the loop's first __syncthreads()

    const u16* atile = xg + (size_t)bt * 131072;
    const u16* btile = wT + ((size_t)(e * 8 + nt)) * 131072;

    int lane = t & 63;
    int wv   = t >> 6;
    int wm   = (wv >> 1) * 64;
    int wn   = (wv & 1) * 64;
    int m    = lane & 15;
    int q    = lane >> 4;

    int aoff = q * 1024 + (wm + m) * 8;   // u16 offset of this lane's A frag in a 32-k slab
    int boff = q * 1024 + (wn + m) * 8;   // same for B within staged LDS slab

    f32x4 acc[4][4];
#pragma unroll
    for (int i = 0; i < 4; ++i)
#pragma unroll
        for (int j = 0; j < 4; ++j)
            acc[i][j] = (f32x4){0.f, 0.f, 0.f, 0.f};

    // prologue: stage B(kb2=0), load A slab0+slab1 of kb2=0 into aA
#pragma unroll
    for (int i = 0; i < 4; ++i)
        gload16(btile + wv * 2048 + i * 512 + lane * 8, &Bs[0][wv * 2048 + i * 512]);

    s16x8 aA0[4], aA1[4], aB0[4], aB1[4];
#pragma unroll
    for (int mt2 = 0; mt2 < 4; ++mt2)
        aA0[mt2] = *(const s16x8*)(atile + aoff + mt2 * 128);
#pragma unroll
    for (int mt2 = 0; mt2 < 4; ++mt2)
        aA1[mt2] = *(const s16x8*)(atile + 4096 + aoff + mt2 * 128);

    // one K-step: compute with (aIn0, aIn1); prefetch step kb2+1 into (aOut0, aOut1)
#define GEMM_STEP(kb2, aIn0, aIn1, aOut0, aOut1)                                       \
    {                                                                                   \
        int cur = (kb2) & 1;                                                            \
        __syncthreads();   /* drain: B(kb2) staged, A prefetch complete */              \
        if ((kb2) < 15) {                                                               \
            const u16* gb = btile + (size_t)((kb2) + 1) * 8192;                         \
            _Pragma("unroll")                                                           \
            for (int i = 0; i < 4; ++i)                                                 \
                gload16(gb + wv * 2048 + i * 512 + lane * 8,                            \
                        &Bs[cur ^ 1][wv * 2048 + i * 512]);                             \
        }                                                                               \
        /* ---- slab 0 ---- */                                                          \
        s16x8 bf[4];                                                                    \
        _Pragma("unroll")                                                               \
        for (int nt2 = 0; nt2 < 4; ++nt2)                                               \
            bf[nt2] = *(const s16x8*)(&Bs[cur][boff + nt2 * 128]);                      \
        _Pragma("unroll")                                                               \
        for (int mt2 = 0; mt2 < 4; ++mt2)                                               \
            _Pragma("unroll")                                                           \
            for (int nt2 = 0; nt2 < 4; ++nt2)                                           \
                acc[mt2][nt2] = __builtin_amdgcn_mfma_f32_16x16x32_bf16(                \
                    aIn0[mt2], bf[nt2], acc[mt2][nt2], 0, 0, 0);                        \
        if ((kb2) < 15) {   /* prefetch BOTH slabs of kb2+1: slab1+drain+stage cover */ \
            _Pragma("unroll")                                                           \
            for (int mt2 = 0; mt2 < 4; ++mt2)                                           \
                aOut0[mt2] = *(const s16x8*)(atile + (size_t)((kb2) + 1) * 8192         \
                                             + aoff + mt2 * 128);                       \
            _Pragma("unroll")                                                           \
            for (int mt2 = 0; mt2 < 4; ++mt2)                                           \
                aOut1[mt2] = *(const s16x8*)(atile + (size_t)((kb2) + 1) * 8192 + 4096  \
                                             + aoff + mt2 * 128);                       \
        }                                                                               \
        /* ---- slab 1 ---- */                                                          \
        _Pragma("unroll")                                                               \
        for (int nt2 = 0; nt2 < 4; ++nt2)                                               \
            bf[nt2] = *(const s16x8*)(&Bs[cur][4096 + boff + nt2 * 128]);               \
        _Pragma("unroll")                                                               \
        for (int mt2 = 0; mt2 < 4; ++mt2)                                               \
            _Pragma("unroll")                                                           \
            for (int nt2 = 0; nt2 < 4; ++nt2)                                           \
                acc[mt2][nt2] = __builtin_amdgcn_mfma_f32_16x16x32_bf16(                \
                    aIn1[mt2], bf[nt2], acc[mt2][nt2], 0, 0, 0);                        \
    }

    for (int kb2 = 0; kb2 < 16; kb2 += 2) {
        GEMM_STEP(kb2,     aA0, aA1, aB0, aB1);
        GEMM_STEP(kb2 + 1, aB0, aB1, aA0, aA1);
    }
#undef GEMM_STEP

    // epilogue: bias + relu, scatter rows by perm
#pragma unroll
    for (int mt2 = 0; mt2 < 4; ++mt2) {
        int rbase = wm + mt2 * 16 + q * 4;
#pragma unroll
        for (int i = 0; i < 4; ++i) {
            int r = rbase + i;
            if (r < mValid) {
                int tok = permS[r];
                float* orow = out + (size_t)tok * OUT_F + nt * 128;
#pragma unroll
                for (int nt2 = 0; nt2 < 4; ++nt2) {
                    int col = wn + nt2 * 16 + m;
                    float v = acc[mt2][nt2][i] + biasS[col];
                    orow[col] = v > 0.f ? v : 0.f;
                }
            }
        }
    }
}

extern "C" void kernel_launch(void* const* d_in, const int* in_sizes, int n_in,
                              void* d_out, int out_size, void* d_ws, size_t ws_size,
                              hipStream_t stream) {
    const float* x    = (const float*)d_in[0];
    const int*   idxs = (const int*)d_in[1];
    const float* w    = (const float*)d_in[2];
    const float* b    = (const float*)d_in[3];
    float* out = (float*)d_out;

    // ws layout: wT u16[16M] (32 MB) | xg u16[80*32*4096] (20 MB) | perm | offs | tile_off
    u16* wT = (u16*)d_ws;
    u16* xg = wT + (size_t)N_MODELS * IN_F * OUT_F;
    int* perm     = (int*)(xg + (size_t)MAX_MT * 32 * 4096);
    int* offs     = perm + N_TOK;
    int* tile_off = offs + (N_MODELS + 1);

    wprep_setup_kernel<<<WBLOCKS + 1, 256, 0, stream>>>(w, idxs, perm, offs, tile_off, wT);
    xprep_kernel<<<XBLOCKS, 256, 0, stream>>>(x, perm, offs, tile_off, xg);
    gemm_kernel<<<8 * MAX_MT, 256, 0, stream>>>(xg, wT, b, perm, offs, tile_off, out);
}